// Round 6
// baseline (68.856 us; speedup 1.0000x reference)
//
#include <hip/hip_runtime.h>
#include <stdint.h>

#define T_TOK 8192
#define DIMK 1024
#define NEXP 8
#define BM 128
#define BN 64
#define BK 64
#define NTK (DIMK / BK)               /* 16 K-steps */
#define MAXROWS (T_TOK + NEXP * BM)   /* 9216 gathered rows incl. padding */
#define MAXTILES (T_TOK / BM + NEXP)  /* 72 row tiles worst case */
#define NT (DIMK / BN)                /* 16 n tiles */
#define NWG (MAXTILES * NT)           /* 1152 blocks, 1152 % 8 == 0 */

typedef __attribute__((ext_vector_type(4))) float f32x4;
typedef __attribute__((ext_vector_type(8))) short short8;
typedef __attribute__((ext_vector_type(8))) unsigned short us8;

__device__ __forceinline__ unsigned short f2bf(float f) {
  uint32_t u = __builtin_bit_cast(uint32_t, f);
  u += 0x7FFFu + ((u >> 16) & 1u);   // RTNE
  return (unsigned short)(u >> 16);
}

__device__ __forceinline__ void gload_lds16(const void* g, void* l) {
  __builtin_amdgcn_global_load_lds(
      (const __attribute__((address_space(1))) void*)g,
      (__attribute__((address_space(3))) void*)l, 16, 0, 0);
}

// ---- prep: histogram + padded offsets + assignment + pad markers -----------
__global__ void k_prep(const int* __restrict__ idx, int* __restrict__ hdr,
                       int* __restrict__ row2tok) {
  __shared__ int h[NEXP];
  __shared__ int cur[NEXP];
  __shared__ int segs[NEXP + 1];
  const int tid = threadIdx.x;   // 256

  if (tid < NEXP) h[tid] = 0;
  __syncthreads();
  for (int i = tid; i < T_TOK; i += 256) atomicAdd(&h[idx[i]], 1);
  __syncthreads();
  if (tid == 0) {
    int off = 0;
    for (int e = 0; e < NEXP; e++) {
      segs[e] = off; cur[e] = off;
      hdr[e] = h[e]; hdr[8 + e] = off;
      off += ((h[e] + BM - 1) >> 7) << 7;
    }
    segs[NEXP] = off;
  }
  __syncthreads();
  for (int e = 0; e < NEXP; e++)
    for (int p = segs[e] + h[e] + tid; p < segs[e + 1]; p += 256) row2tok[p] = -1;
  for (int p = segs[NEXP] + tid; p < MAXROWS; p += 256) row2tok[p] = -1;
  for (int i = tid; i < T_TOK; i += 256) {
    int e = idx[i];
    int pos = atomicAdd(&cur[e], 1);
    row2tok[pos] = i;
  }
}

// ---- fused W conversion + X gather (both fp32 -> bf16, 8 elems/thread) -----
__global__ void k_convgather(const float* __restrict__ W, const float* __restrict__ X,
                             const int* __restrict__ row2tok,
                             unsigned short* __restrict__ Wb,
                             unsigned short* __restrict__ Xg) {
  const int tid = threadIdx.x;
  const int b = blockIdx.x;
  const float* src;
  unsigned short* dst;
  if (b < 4096) {
    size_t base = (size_t)b * 2048 + tid * 8;
    src = W + base;
    dst = Wb + base;
  } else {
    int r = (b - 4096) * 2 + (tid >> 7);
    int t = row2tok[r];
    if (t < 0) return;  // pad row: its outputs are never stored
    int col = (tid & 127) * 8;
    src = X + (size_t)t * DIMK + col;
    dst = Xg + (size_t)r * DIMK + col;
  }
  f32x4 v0 = *(const f32x4*)src;
  f32x4 v1 = *(const f32x4*)(src + 4);
  us8 o;
  o[0] = f2bf(v0[0]); o[1] = f2bf(v0[1]); o[2] = f2bf(v0[2]); o[3] = f2bf(v0[3]);
  o[4] = f2bf(v1[0]); o[5] = f2bf(v1[1]); o[6] = f2bf(v1[2]); o[7] = f2bf(v1[3]);
  *(us8*)dst = o;
}

// ---- grouped GEMM: C[row] = Xg[row] . Wb[e]^T ------------------------------
// T3+T4: double-buffered LDS, depth-2 prefetch, COUNTED vmcnt (never 0 in the
// main loop) + raw s_barrier. Each wave issues exactly 6 global_load_lds per
// STAGE; steady state 12 in flight; vmcnt(6) = "oldest STAGE retired".
__global__ __launch_bounds__(256, 4) void k_gemm(
    const unsigned short* __restrict__ Xg, const unsigned short* __restrict__ Wb,
    const int* __restrict__ hdr, const int* __restrict__ row2tok,
    float* __restrict__ out) {
  __shared__ unsigned short A_lds[2][BM * BK];  // 2 x 16 KB
  __shared__ unsigned short B_lds[2][BN * BK];  // 2 x 8 KB  (48 KB total)

  // XCD chunk remap: NWG=1152 % 8 == 0 -> wgid = xcd*144 + orig/8.
  const int orig = blockIdx.x;
  const int wgid = (orig & 7) * (NWG / 8) + (orig >> 3);
  int tile = wgid >> 4;               // row tile
  const int n0 = (wgid & 15) * BN;    // output column base

  // map row tile -> (expert, gathered row0) over padded segments
  int e = -1, row0 = 0;
  for (int i = 0; i < NEXP; i++) {
    int te = (hdr[i] + BM - 1) >> 7;
    if (e < 0) {
      if (tile < te) { e = i; row0 = (hdr[8 + i] & ~127) + tile * BM; }
      else tile -= te;
    }
  }
  if (e < 0) return;

  const int tid = threadIdx.x;
  const int lane = tid & 63;
  const int wid = tid >> 6;
  const int wr = wid >> 1, wc = wid & 1;   // wave tile 64x32

  // staging: lane covers 16B at LDS linear (chunk*1024 + lane*16).
  // LDS row = chunk*8 + (lane>>3); read side XORs col by (row&7)<<4, so the
  // *source* column carries the same XOR (both-sides-or-neither).
  const int st_r = lane >> 3;
  const int st_cb = ((lane & 7) ^ st_r) << 4;

  const char* a_base = (const char*)Xg + (size_t)row0 * (DIMK * 2);
  const char* b_base = (const char*)Wb + ((size_t)e * DIMK * DIMK + (size_t)n0 * DIMK) * 2;

  f32x4 acc[4][2];
  const f32x4 fzero = {0.f, 0.f, 0.f, 0.f};
#pragma unroll
  for (int m = 0; m < 4; m++)
#pragma unroll
    for (int n = 0; n < 2; n++) acc[m][n] = fzero;

  const int rsel = lane & 15;
  const int swz_r = (lane & 7) << 4;
  const int kgrp = (lane >> 4) << 4;

  int a_row_b[4], b_row_b[2];
#pragma unroll
  for (int m = 0; m < 4; m++) a_row_b[m] = (wr * 64 + m * 16 + rsel) * (BK * 2);
#pragma unroll
  for (int n = 0; n < 2; n++) b_row_b[n] = (wc * 32 + n * 16 + rsel) * (BK * 2);

#define STAGE(kt, buf)                                                         \
  {                                                                            \
    const int k0b = (kt) * (BK * 2);                                           \
    _Pragma("unroll") for (int j = 0; j < 4; j++) {                            \
      int c = wid * 4 + j;                                                     \
      int r = c * 8 + st_r;                                                    \
      gload_lds16(a_base + (size_t)r * (DIMK * 2) + k0b + st_cb,               \
                  (char*)A_lds[buf] + c * 1024);                               \
    }                                                                          \
    _Pragma("unroll") for (int j = 0; j < 2; j++) {                            \
      int c = wid * 2 + j;                                                     \
      int r = c * 8 + st_r;                                                    \
      gload_lds16(b_base + (size_t)r * (DIMK * 2) + k0b + st_cb,               \
                  (char*)B_lds[buf] + c * 1024);                               \
    }                                                                          \
  }

#define COMPUTE(buf)                                                           \
  {                                                                            \
    _Pragma("unroll") for (int ks = 0; ks < 2; ks++) {                         \
      const int kb = ks * 64 + kgrp;                                           \
      short8 av[4], bv[2];                                                     \
      _Pragma("unroll") for (int m = 0; m < 4; m++)                            \
          av[m] = *(const short8*)((const char*)A_lds[buf] + a_row_b[m] +      \
                                   (kb ^ swz_r));                              \
      _Pragma("unroll") for (int n = 0; n < 2; n++)                            \
          bv[n] = *(const short8*)((const char*)B_lds[buf] + b_row_b[n] +      \
                                   (kb ^ swz_r));                              \
      _Pragma("unroll") for (int m = 0; m < 4; m++)                            \
          _Pragma("unroll") for (int n = 0; n < 2; n++)                        \
              acc[m][n] = __builtin_amdgcn_mfma_f32_16x16x32_bf16(             \
                  av[m], bv[n], acc[m][n], 0, 0, 0);                           \
    }                                                                          \
  }

  STAGE(0, 0);
  STAGE(1, 1);   // 12 loads in flight
#pragma unroll 2
  for (int kt = 0; kt < NTK - 2; kt++) {          // kt = 0..13
    asm volatile("s_waitcnt vmcnt(6)" ::: "memory");  // STAGE(kt) retired
    __builtin_amdgcn_s_barrier();                     // buf[kt&1] full everywhere
    __builtin_amdgcn_sched_barrier(0);                // no ds_read hoist above
    COMPUTE(kt & 1);
    __builtin_amdgcn_s_barrier();                     // all reads of buf done
    STAGE(kt + 2, kt & 1);                            // overwrite freed buffer
  }
  // kt = 14: still 12 in flight, no further stage
  asm volatile("s_waitcnt vmcnt(6)" ::: "memory");
  __builtin_amdgcn_s_barrier();
  __builtin_amdgcn_sched_barrier(0);
  COMPUTE(0);
  // kt = 15: drain the last 6
  asm volatile("s_waitcnt vmcnt(0)" ::: "memory");
  __builtin_amdgcn_s_barrier();
  __builtin_amdgcn_sched_barrier(0);
  COMPUTE(1);
#undef STAGE
#undef COMPUTE

  // epilogue: scatter rows back to tokens; pad rows have row2tok == -1
  const int rg4 = (lane >> 4) * 4;
#pragma unroll
  for (int m = 0; m < 4; m++) {
#pragma unroll
    for (int i = 0; i < 4; i++) {
      int rg = row0 + wr * 64 + m * 16 + rg4 + i;
      int tok = row2tok[rg];
      if (tok >= 0) {
        float* po = out + (size_t)tok * DIMK + n0 + wc * 32 + rsel;
#pragma unroll
        for (int n = 0; n < 2; n++) po[n * 16] = acc[m][n][i];
      }
    }
  }
}

extern "C" void kernel_launch(void* const* d_in, const int* in_sizes, int n_in,
                              void* d_out, int out_size, void* d_ws, size_t ws_size,
                              hipStream_t stream) {
  const float* X = (const float*)d_in[0];
  const float* W = (const float*)d_in[1];
  const int* idx = (const int*)d_in[2];
  float* out = (float*)d_out;
  char* ws = (char*)d_ws;

  int* hdr = (int*)ws;                                     // 64 ints
  int* row2tok = (int*)(ws + 256);                         // 9216 ints
  unsigned short* Wb = (unsigned short*)(ws + 65536);      // 16 MiB bf16 W
  unsigned short* Xg = (unsigned short*)(ws + 65536 + 16777216);  // 18 MiB bf16 gathered X

  k_prep<<<1, 256, 0, stream>>>(idx, hdr, row2tok);
  k_convgather<<<4096 + MAXROWS / 2, 256, 0, stream>>>(W, X, row2tok, Wb, Xg);

  k_gemm<<<NWG, 256, 0, stream>>>(Xg, Wb, hdr, row2tok, out);
}

// Round 7
// 61.734 us; speedup vs baseline: 1.1154x; 1.1154x over previous
//
#include <hip/hip_runtime.h>
#include <stdint.h>

#define T_TOK 8192
#define DIMK 1024
#define NEXP 8
#define BM 128
#define BN 64
#define BK 64
#define NTK (DIMK / BK)               /* 16 K-steps */
#define MAXROWS (T_TOK + NEXP * BM)   /* 9216 gathered rows incl. padding */
#define MAXTILES (T_TOK / BM + NEXP)  /* 72 row tiles worst case */
#define NT (DIMK / BN)                /* 16 n tiles */
#define NWG (MAXTILES * NT)           /* 1152 blocks, 1152 % 8 == 0 */

typedef __attribute__((ext_vector_type(4))) float f32x4;
typedef __attribute__((ext_vector_type(8))) short short8;
typedef __attribute__((ext_vector_type(8))) unsigned short us8;

__device__ __forceinline__ unsigned short f2bf(float f) {
  uint32_t u = __builtin_bit_cast(uint32_t, f);
  u += 0x7FFFu + ((u >> 16) & 1u);   // RTNE
  return (unsigned short)(u >> 16);
}

__device__ __forceinline__ void gload_lds16(const void* g, void* l) {
  __builtin_amdgcn_global_load_lds(
      (const __attribute__((address_space(1))) void*)g,
      (__attribute__((address_space(3))) void*)l, 16, 0, 0);
}

// ---- fused: prep (block 0) || W fp32->bf16 || X fp32->bf16 -----------------
// The three parts are mutually independent (prep writes hdr/row2tok; the
// converts are pure elementwise), so no cross-block ordering is assumed.
__global__ void k_prep_conv(const int* __restrict__ idx, const float* __restrict__ W,
                            const float* __restrict__ X, int* __restrict__ hdr,
                            int* __restrict__ row2tok, unsigned short* __restrict__ Wb,
                            unsigned short* __restrict__ Xb) {
  const int tid = threadIdx.x;
  const int b = blockIdx.x;
  if (b == 0) {
    __shared__ int h[NEXP];
    __shared__ int cur[NEXP];
    __shared__ int segs[NEXP + 1];
    if (tid < NEXP) h[tid] = 0;
    __syncthreads();
    for (int i = tid; i < T_TOK; i += 256) atomicAdd(&h[idx[i]], 1);
    __syncthreads();
    if (tid == 0) {
      int off = 0;
      for (int e = 0; e < NEXP; e++) {
        segs[e] = off; cur[e] = off;
        hdr[e] = h[e]; hdr[8 + e] = off;
        off += ((h[e] + BM - 1) >> 7) << 7;
      }
      segs[NEXP] = off;
    }
    __syncthreads();
    for (int e = 0; e < NEXP; e++)
      for (int p = segs[e] + h[e] + tid; p < segs[e + 1]; p += 256) row2tok[p] = -1;
    for (int p = segs[NEXP] + tid; p < MAXROWS; p += 256) row2tok[p] = -1;
    for (int i = tid; i < T_TOK; i += 256) {
      int e = idx[i];
      int pos = atomicAdd(&cur[e], 1);
      row2tok[pos] = i;
    }
    return;
  }
  const float* src;
  unsigned short* dst;
  if (b <= 4096) {                    // W: 4096 blocks x 2048 elems
    size_t base = (size_t)(b - 1) * 2048 + tid * 8;
    src = W + base; dst = Wb + base;
  } else {                            // X: 4096 blocks x 2048 elems, token order
    size_t base = (size_t)(b - 4097) * 2048 + tid * 8;
    src = X + base; dst = Xb + base;
  }
  f32x4 v0 = *(const f32x4*)src;
  f32x4 v1 = *(const f32x4*)(src + 4);
  us8 o;
  o[0] = f2bf(v0[0]); o[1] = f2bf(v0[1]); o[2] = f2bf(v0[2]); o[3] = f2bf(v0[3]);
  o[4] = f2bf(v1[0]); o[5] = f2bf(v1[1]); o[6] = f2bf(v1[2]); o[7] = f2bf(v1[3]);
  *(us8*)dst = o;
}

// ---- grouped GEMM with fused A-gather: C[row] = Xb[row2tok[row]] . Wb[e]^T --
// R5 single-buffer 2-barrier structure (proven fastest: 24 KB LDS keeps all
// ~4.5 blocks/CU co-resident in one round; cross-block overlap hides latency).
// A-tile staging gathers scattered token rows via PER-LANE global addresses
// (global_load_lds's source is per-lane, m173); LDS dest stays linear.
__global__ __launch_bounds__(256, 4) void k_gemm(
    const unsigned short* __restrict__ Xb, const unsigned short* __restrict__ Wb,
    const int* __restrict__ hdr, const int* __restrict__ row2tok,
    float* __restrict__ out) {
  __shared__ unsigned short A_lds[BM * BK];  // 16 KB
  __shared__ unsigned short B_lds[BN * BK];  // 8 KB

  // XCD chunk remap: NWG=1152 % 8 == 0 -> wgid = xcd*144 + orig/8.
  const int orig = blockIdx.x;
  const int wgid = (orig & 7) * (NWG / 8) + (orig >> 3);
  int tile = wgid >> 4;               // row tile
  const int n0 = (wgid & 15) * BN;    // output column base

  // map row tile -> (expert, gathered row0) over padded segments
  int e = -1, row0 = 0;
  for (int i = 0; i < NEXP; i++) {
    int te = (hdr[i] + BM - 1) >> 7;
    if (e < 0) {
      if (tile < te) { e = i; row0 = hdr[8 + i] + tile * BM; }
      else tile -= te;
    }
  }
  if (e < 0) return;

  const int tid = threadIdx.x;
  const int lane = tid & 63;
  const int wid = tid >> 6;
  const int wr = wid >> 1, wc = wid & 1;   // wave tile 64x32

  // staging: lane covers 16B at LDS linear (chunk*1024 + lane*16).
  // LDS row = chunk*8 + (lane>>3); read side XORs col by (row&7)<<4, so the
  // *source* column carries the same XOR (both-sides-or-neither).
  const int st_r = lane >> 3;
  const int st_cb = ((lane & 7) ^ st_r) << 4;

  // resolve this lane's 4 A-row tokens ONCE (rows fixed across K-steps).
  // pad rows (tok=-1) clamp to row 0: garbage values, outputs never stored.
  const char* a_lane_base[4];
#pragma unroll
  for (int j = 0; j < 4; j++) {
    int r = (wid * 4 + j) * 8 + st_r;
    int tok = row2tok[row0 + r];
    if (tok < 0) tok = 0;
    a_lane_base[j] = (const char*)Xb + (size_t)tok * (DIMK * 2) + st_cb;
  }
  const char* b_base = (const char*)Wb + ((size_t)e * DIMK * DIMK + (size_t)n0 * DIMK) * 2;

  f32x4 acc[4][2];
  const f32x4 fzero = {0.f, 0.f, 0.f, 0.f};
#pragma unroll
  for (int m = 0; m < 4; m++)
#pragma unroll
    for (int n = 0; n < 2; n++) acc[m][n] = fzero;

  const int rsel = lane & 15;
  const int swz_r = (lane & 7) << 4;
  const int kgrp = (lane >> 4) << 4;

  int a_row_b[4], b_row_b[2];
#pragma unroll
  for (int m = 0; m < 4; m++) a_row_b[m] = (wr * 64 + m * 16 + rsel) * (BK * 2);
#pragma unroll
  for (int n = 0; n < 2; n++) b_row_b[n] = (wc * 32 + n * 16 + rsel) * (BK * 2);

  for (int kt = 0; kt < NTK; kt++) {
    const int k0b = kt * (BK * 2);
    // stage A (gathered, 16 chunks) + B (8 chunks); 6 gload_lds per wave
#pragma unroll
    for (int j = 0; j < 4; j++) {
      int c = wid * 4 + j;
      gload_lds16(a_lane_base[j] + k0b, (char*)A_lds + c * 1024);
    }
#pragma unroll
    for (int j = 0; j < 2; j++) {
      int c = wid * 2 + j;
      int r = c * 8 + st_r;
      gload_lds16(b_base + (size_t)r * (DIMK * 2) + k0b + st_cb, (char*)B_lds + c * 1024);
    }
    __syncthreads();
#pragma unroll
    for (int ks = 0; ks < 2; ks++) {
      const int kb = ks * 64 + kgrp;
      short8 av[4], bv[2];
#pragma unroll
      for (int m = 0; m < 4; m++)
        av[m] = *(const short8*)((const char*)A_lds + a_row_b[m] + (kb ^ swz_r));
#pragma unroll
      for (int n = 0; n < 2; n++)
        bv[n] = *(const short8*)((const char*)B_lds + b_row_b[n] + (kb ^ swz_r));
#pragma unroll
      for (int m = 0; m < 4; m++)
#pragma unroll
        for (int n = 0; n < 2; n++)
          acc[m][n] = __builtin_amdgcn_mfma_f32_16x16x32_bf16(av[m], bv[n], acc[m][n], 0, 0, 0);
    }
    __syncthreads();
  }

  // epilogue: scatter rows back to tokens; pad rows have row2tok == -1
  const int rg4 = (lane >> 4) * 4;
#pragma unroll
  for (int m = 0; m < 4; m++) {
#pragma unroll
    for (int i = 0; i < 4; i++) {
      int rg = row0 + wr * 64 + m * 16 + rg4 + i;
      int tok = row2tok[rg];
      if (tok >= 0) {
        float* po = out + (size_t)tok * DIMK + n0 + wc * 32 + rsel;
#pragma unroll
        for (int n = 0; n < 2; n++) po[n * 16] = acc[m][n][i];
      }
    }
  }
}

extern "C" void kernel_launch(void* const* d_in, const int* in_sizes, int n_in,
                              void* d_out, int out_size, void* d_ws, size_t ws_size,
                              hipStream_t stream) {
  const float* X = (const float*)d_in[0];
  const float* W = (const float*)d_in[1];
  const int* idx = (const int*)d_in[2];
  float* out = (float*)d_out;
  char* ws = (char*)d_ws;

  int* hdr = (int*)ws;                                     // 64 ints
  int* row2tok = (int*)(ws + 256);                         // 9216 ints
  unsigned short* Wb = (unsigned short*)(ws + 65536);      // 16 MiB bf16 W
  unsigned short* Xb = (unsigned short*)(ws + 65536 + 16777216);  // 16 MiB bf16 X (token order)

  k_prep_conv<<<8193, 256, 0, stream>>>(idx, W, X, hdr, row2tok, Wb, Xb);
  k_gemm<<<NWG, 256, 0, stream>>>(Xb, Wb, hdr, row2tok, out);
}